// Round 2
// baseline (173.339 us; speedup 1.0000x reference)
//
#include <hip/hip_runtime.h>
#include <hip/hip_bf16.h>
#include <stdint.h>

// Problem constants
#define B_   16
#define IC_  16
#define L_   4096
#define OC_  256
#define NC_  8
#define CD_  16
#define K_   9
#define IK_  (IC_*K_)   // 144
#define ROWP 4112       // padded row stride (floats); data at [4..4099], zeros [0..3] & [4100..4111]

// workspace layout (float element offsets)
#define WS_XC  0u                          // 128*16 rows * ROWP   (xc[m*16+k][i][ROWP])
#define WS_X   (128u*16u*ROWP)             // 16 rows * ROWP       (X[i][ROWP])
#define WS_CW  (WS_X + 16u*ROWP)           // 128*144              (cw[n*16+k][i*9+t])
#define WS_CB  (WS_CW + 128u*IK_)          // 128                  (cb[n*16+k])
#define WS_U   (WS_CB + 128u)              // 128*4096             (U[k*8+n][s])

// ---------------- K2: combined conv->caps weights ----------------
// cw[n,k,i,t] = sum_c caps_w[n,k,c]*conv_w[c,i,t];  cb[n,k] = sum_c caps_w[n,k,c]*conv_b[c] + caps_b[n,k]
__global__ void k_cw(const float* __restrict__ caps_w,
                     const float* __restrict__ conv_w,
                     const float* __restrict__ conv_b,
                     const float* __restrict__ caps_b,
                     float* __restrict__ ws) {
    __shared__ float cwl[OC_];
    const int nk  = blockIdx.x;     // n*16+k
    const int tid = threadIdx.x;    // 256 threads
    cwl[tid] = caps_w[nk*OC_ + tid];
    __syncthreads();
    if (tid < IK_) {
        float a = 0.f;
        for (int c = 0; c < OC_; ++c)
            a += cwl[c] * conv_w[c*IK_ + tid];
        ws[WS_CW + nk*IK_ + tid] = a;
    } else if (tid == IK_) {
        float a = 0.f;
        for (int c = 0; c < OC_; ++c)
            a += cwl[c] * conv_b[c];
        ws[WS_CB + nk] = a + caps_b[nk];
    }
}

// ---------------- K3: softmax(W) mix of x -> xc, and X = sum_b x ----------------
// xc[m,k,i,sp] = sum_b c[m,b,k]*x[b,i,sp];  X[i,sp] = sum_b x[b,i,sp]
__global__ void k_xc(const float* __restrict__ x,
                     const float* __restrict__ W,
                     float* __restrict__ ws) {
    __shared__ float cl[128*16];    // c[mk][b]
    const int tid  = threadIdx.x;
    const int i    = blockIdx.x >> 4;
    const int tile = blockIdx.x & 15;
    if (tid < 128) {                 // one softmax per (m,k)
        const int m = tid >> 4, k = tid & 15;
        float w[16], mx = -1e30f;
        #pragma unroll
        for (int b = 0; b < 16; ++b) {
            w[b] = W[m*256 + b*16 + k];
            mx = fmaxf(mx, w[b]);
        }
        float sum = 0.f;
        #pragma unroll
        for (int b = 0; b < 16; ++b) { w[b] = __expf(w[b] - mx); sum += w[b]; }
        const float inv = 1.f / sum;
        #pragma unroll
        for (int b = 0; b < 16; ++b) cl[tid*16 + b] = w[b] * inv;
    }
    __syncthreads();
    const int sp = tile*256 + tid;
    float xv[16], Xs = 0.f;
    #pragma unroll
    for (int b = 0; b < 16; ++b) {
        xv[b] = x[b*(IC_*L_) + i*L_ + sp];
        Xs += xv[b];
    }
    float* Xrow = ws + WS_X + (size_t)i*ROWP;
    Xrow[4 + sp] = Xs;
    if (tile == 0  && tid < 4)  Xrow[tid] = 0.f;
    if (tile == 15 && tid < 12) Xrow[4100 + tid] = 0.f;
    for (int mk = 0; mk < 128; ++mk) {
        float a = 0.f;
        #pragma unroll
        for (int b = 0; b < 16; ++b) a += cl[mk*16 + b] * xv[b];
        float* row = ws + WS_XC + (size_t)(mk*16 + i)*ROWP;
        row[4 + sp] = a;
        if (tile == 0  && tid < 4)  row[tid] = 0.f;
        if (tile == 15 && tid < 12) row[4100 + tid] = 0.f;
    }
}

// ---------------- K4: U[k,n,s] = conv(X) with cw + 16*cb ----------------
__global__ void k_u(const float* __restrict__ wsc, float* __restrict__ ws) {
    const int tid = threadIdx.x;
    const int k = blockIdx.x >> 3, n = blockIdx.x & 7;
    __shared__ float cwl[IK_ + 1];
    if (tid < IK_)  cwl[tid] = wsc[WS_CW + (n*16 + k)*IK_ + tid];
    if (tid == IK_) cwl[IK_] = wsc[WS_CB + n*16 + k];
    __syncthreads();
    float acc[16];
    #pragma unroll
    for (int j = 0; j < 16; ++j) acc[j] = 0.f;
    const int base = tid * 16;
    for (int i = 0; i < IC_; ++i) {
        const float* row = wsc + WS_X + (size_t)i*ROWP + base;   // window [base, base+24)
        float xw[24];
        #pragma unroll
        for (int q = 0; q < 6; ++q) {
            float4 v = *(const float4*)(row + q*4);
            xw[4*q+0] = v.x; xw[4*q+1] = v.y; xw[4*q+2] = v.z; xw[4*q+3] = v.w;
        }
        #pragma unroll
        for (int t = 0; t < 9; ++t) {
            const float w = cwl[i*9 + t];
            #pragma unroll
            for (int j = 0; j < 16; ++j) acc[j] += w * xw[j + t];
        }
    }
    const float cb16 = 16.f * cwl[IK_];
    float4* Up = (float4*)(ws + WS_U + (size_t)blockIdx.x*4096 + base);
    #pragma unroll
    for (int q = 0; q < 4; ++q)
        Up[q] = make_float4(acc[4*q+0]+cb16, acc[4*q+1]+cb16, acc[4*q+2]+cb16, acc[4*q+3]+cb16);
}

// ---------------- block-wide sum over 256 threads (4 waves) ----------------
__device__ __forceinline__ float block_sum(float v, float* red, int tid) {
    #pragma unroll
    for (int off = 32; off; off >>= 1) v += __shfl_down(v, off, 64);
    if ((tid & 63) == 0) red[tid >> 6] = v;
    __syncthreads();
    const float r = red[0] + red[1] + red[2] + red[3];
    __syncthreads();   // allow red reuse by the next call
    return r;
}

// ---------------- K5: s0 conv + collapsed routing + output ----------------
__global__ void __launch_bounds__(256) k_main(const float* __restrict__ wsc,
                                              float* __restrict__ out) {
    const int tid = threadIdx.x;
    // bx = n*128 + mk so the 8 n-blocks sharing xc[m,k] land on the same XCD (bx%8 == mk%8)
    const int n  = blockIdx.x >> 7;
    const int mk = blockIdx.x & 127;
    const int k  = mk & 15;
    __shared__ float cwl[IK_ + 1];
    __shared__ float red[8];
    if (tid < IK_)  cwl[tid] = wsc[WS_CW + (n*16 + k)*IK_ + tid];
    if (tid == IK_) cwl[IK_] = wsc[WS_CB + n*16 + k];
    __syncthreads();

    float acc[16];
    #pragma unroll
    for (int j = 0; j < 16; ++j) acc[j] = 0.f;
    const int base = tid * 16;           // this thread owns s in [base, base+16)
    for (int i = 0; i < IC_; ++i) {
        const float* row = wsc + WS_XC + (size_t)(mk*16 + i)*ROWP + base;  // padded: idx base+j+t
        float xw[24];
        #pragma unroll
        for (int q = 0; q < 6; ++q) {
            float4 v = *(const float4*)(row + q*4);
            xw[4*q+0] = v.x; xw[4*q+1] = v.y; xw[4*q+2] = v.z; xw[4*q+3] = v.w;
        }
        #pragma unroll
        for (int t = 0; t < 9; ++t) {
            const float w = cwl[i*9 + t];
            #pragma unroll
            for (int j = 0; j < 16; ++j) acc[j] += w * xw[j + t];
        }
    }
    const float cb = cwl[IK_];
    #pragma unroll
    for (int j = 0; j < 16; ++j) acc[j] += cb;        // acc = s0

    float Uv[16];
    const float* Urow = wsc + WS_U + (size_t)(k*8 + n)*4096 + base;
    #pragma unroll
    for (int q = 0; q < 4; ++q) {
        float4 v = *(const float4*)(Urow + q*4);
        Uv[4*q+0] = v.x; Uv[4*q+1] = v.y; Uv[4*q+2] = v.z; Uv[4*q+3] = v.w;
    }

    // iteration 0: r0 from ||s0||
    float p = 0.f;
    #pragma unroll
    for (int j = 0; j < 16; ++j) p += acc[j]*acc[j];
    const float n0 = block_sum(p, red, tid);
    const float r0 = __fsqrt_rn(n0) / (1.f + n0);

    // s1 = s0 * (1 + r0*s0*U)
    float s1[16];
    p = 0.f;
    #pragma unroll
    for (int j = 0; j < 16; ++j) {
        s1[j] = acc[j] * (1.f + r0*acc[j]*Uv[j]);
        p += s1[j]*s1[j];
    }
    const float n1 = block_sum(p, red, tid);
    const float r1 = __fsqrt_rn(n1) / (1.f + n1);

    // s2 = s0 + r1*s1^2*U
    float s2[16];
    p = 0.f;
    #pragma unroll
    for (int j = 0; j < 16; ++j) {
        s2[j] = acc[j] + r1*s1[j]*s1[j]*Uv[j];
        p += s2[j]*s2[j];
    }
    const float n2 = block_sum(p, red, tid);
    const float r2 = __fsqrt_rn(n2) / (1.f + n2);

    // out[m,k,n,s] = s2 * r2  (fp32), 16 values -> four 16B stores
    float4* po = (float4*)(out + (size_t)(mk*8 + n)*4096 + base);
    #pragma unroll
    for (int q = 0; q < 4; ++q)
        po[q] = make_float4(s2[4*q+0]*r2, s2[4*q+1]*r2, s2[4*q+2]*r2, s2[4*q+3]*r2);
}

extern "C" void kernel_launch(void* const* d_in, const int* in_sizes, int n_in,
                              void* d_out, int out_size, void* d_ws, size_t ws_size,
                              hipStream_t stream) {
    const float* x      = (const float*)d_in[0];
    const float* conv_w = (const float*)d_in[1];
    const float* conv_b = (const float*)d_in[2];
    const float* caps_w = (const float*)d_in[3];
    const float* caps_b = (const float*)d_in[4];
    const float* W      = (const float*)d_in[5];
    float* ws  = (float*)d_ws;
    float* out = (float*)d_out;

    hipLaunchKernelGGL(k_cw,   dim3(128),  dim3(256), 0, stream, caps_w, conv_w, conv_b, caps_b, ws);
    hipLaunchKernelGGL(k_xc,   dim3(256),  dim3(256), 0, stream, x, W, ws);
    hipLaunchKernelGGL(k_u,    dim3(128),  dim3(256), 0, stream, ws, ws);
    hipLaunchKernelGGL(k_main, dim3(1024), dim3(256), 0, stream, ws, out);
}

// Round 3
// 140.811 us; speedup vs baseline: 1.2310x; 1.2310x over previous
//
#include <hip/hip_runtime.h>
#include <stdint.h>

// Problem constants: B=IC=16, L=4096, OC=256, NC=8, CD=16, K=9
#define IK_  144          // IC*K
// workspace layout (float element offsets)
#define WS_CW  0u         // cw[nk=n*16+k][144]
#define WS_CB  18432u     // cb[nk]
#define WS_U   18560u     // u[b][nk][s] at WS_U + ((b*128+nk)<<12) + s  (33.5 MB)

// ---------------- K0: folded conv->caps weights ----------------
// cw[nk,i,t] = sum_c caps_w[nk,c]*conv_w[c,i,t];  cb[nk] = sum_c caps_w[nk,c]*conv_b[c] + caps_b[nk]
__global__ void k_cw(const float* __restrict__ caps_w,
                     const float* __restrict__ conv_w,
                     const float* __restrict__ conv_b,
                     const float* __restrict__ caps_b,
                     float* __restrict__ ws) {
    __shared__ float cwl[256];
    const int nk  = blockIdx.x;
    const int tid = threadIdx.x;
    cwl[tid] = caps_w[nk*256 + tid];
    __syncthreads();
    if (tid < IK_) {
        float a0 = 0.f, a1 = 0.f, a2 = 0.f, a3 = 0.f;
        for (int c = 0; c < 256; c += 4) {
            a0 += cwl[c+0] * conv_w[(c+0)*IK_ + tid];
            a1 += cwl[c+1] * conv_w[(c+1)*IK_ + tid];
            a2 += cwl[c+2] * conv_w[(c+2)*IK_ + tid];
            a3 += cwl[c+3] * conv_w[(c+3)*IK_ + tid];
        }
        ws[WS_CW + nk*IK_ + tid] = (a0 + a1) + (a2 + a3);
    } else if (tid == IK_) {
        float a = 0.f;
        for (int c = 0; c < 256; ++c) a += cwl[c] * conv_b[c];
        ws[WS_CB + nk] = a + caps_b[nk];
    }
}

// ---------------- K1: u[b,nk,s] = conv(x[b], cw[nk]) + cb[nk] ----------------
// grid 2048 = (pair p 0..63, half h 0..1, b 0..15); bx%16 = b so same-b blocks share an XCD's L2
__global__ void __launch_bounds__(256) k_conv(const float* __restrict__ x,
                                              const float* __restrict__ wsc,
                                              float* __restrict__ ws) {
    const int tid = threadIdx.x;
    const int b   = blockIdx.x & 15;
    const int ph  = blockIdx.x >> 4;
    const int p   = ph >> 1;        // nk pair: 2p, 2p+1
    const int h   = ph & 1;         // s half
    __shared__ float cw2[2][152];
    for (int idx = tid; idx < 290; idx += 256) {
        const int which = (idx >= 145) ? 1 : 0;
        const int r = idx - which*145;
        cw2[which][r] = (r < IK_) ? wsc[WS_CW + (2*p+which)*IK_ + r]
                                  : wsc[WS_CB + 2*p + which];
    }
    __syncthreads();

    float acc[2][8];
    #pragma unroll
    for (int c = 0; c < 2; ++c)
        #pragma unroll
        for (int j = 0; j < 8; ++j) acc[c][j] = 0.f;

    const int  S0  = h*2048 + tid*8;          // this thread: s in [S0, S0+8)
    const bool glo = (h == 0) && (tid == 0);
    const bool ghi = (h == 1) && (tid == 255);
    const float* xb = x + (b << 16);

    #pragma unroll 2
    for (int i = 0; i < 16; ++i) {
        const float* row = xb + (i << 12);
        // window w[0..15] = x[b,i, S0-4 .. S0+12), edges zero-padded
        float4 v0 = *(const float4*)(row + (glo ? S0     : S0 - 4));
        float4 v1 = *(const float4*)(row + S0);
        float4 v2 = *(const float4*)(row + S0 + 4);
        float4 v3 = *(const float4*)(row + (ghi ? S0 + 4 : S0 + 8));
        float w[16];
        w[0]=v0.x; w[1]=v0.y; w[2]=v0.z; w[3]=v0.w;
        w[4]=v1.x; w[5]=v1.y; w[6]=v1.z; w[7]=v1.w;
        w[8]=v2.x; w[9]=v2.y; w[10]=v2.z; w[11]=v2.w;
        w[12]=v3.x; w[13]=v3.y; w[14]=v3.z; w[15]=v3.w;
        if (glo) { w[0]=0.f; w[1]=0.f; w[2]=0.f; w[3]=0.f; }
        if (ghi) { w[12]=0.f; w[13]=0.f; w[14]=0.f; w[15]=0.f; }
        #pragma unroll
        for (int t = 0; t < 9; ++t) {
            const float wa = cw2[0][i*9 + t];
            const float wb = cw2[1][i*9 + t];
            #pragma unroll
            for (int j = 0; j < 8; ++j) {
                acc[0][j] = fmaf(wa, w[j+t], acc[0][j]);
                acc[1][j] = fmaf(wb, w[j+t], acc[1][j]);
            }
        }
    }
    const float cb0 = cw2[0][144], cb1 = cw2[1][144];
    float* u0 = ws + WS_U + (size_t)(((b << 7) + 2*p) << 12) + S0;
    ((float4*)u0)[0] = make_float4(acc[0][0]+cb0, acc[0][1]+cb0, acc[0][2]+cb0, acc[0][3]+cb0);
    ((float4*)u0)[1] = make_float4(acc[0][4]+cb0, acc[0][5]+cb0, acc[0][6]+cb0, acc[0][7]+cb0);
    float* u1 = u0 + 4096;
    ((float4*)u1)[0] = make_float4(acc[1][0]+cb1, acc[1][1]+cb1, acc[1][2]+cb1, acc[1][3]+cb1);
    ((float4*)u1)[1] = make_float4(acc[1][4]+cb1, acc[1][5]+cb1, acc[1][6]+cb1, acc[1][7]+cb1);
}

// ---------------- block-wide paired sum over 256 threads ----------------
__device__ __forceinline__ void block_sum2(float& a, float& b, float (*red)[2], int tid) {
    #pragma unroll
    for (int off = 32; off; off >>= 1) {
        a += __shfl_down(a, off, 64);
        b += __shfl_down(b, off, 64);
    }
    if ((tid & 63) == 0) { red[tid >> 6][0] = a; red[tid >> 6][1] = b; }
    __syncthreads();
    a = (red[0][0] + red[1][0]) + (red[2][0] + red[3][0]);
    b = (red[0][1] + red[1][1]) + (red[2][1] + red[3][1]);
    __syncthreads();
}

// ---------------- K2: routing. block = (mp 0..3, nk 0..127), 2 m per block ----------------
// bx = mp*128 + nk : same-nk blocks (sharing u rows) land on the same XCD
__global__ void __launch_bounds__(256) k_route(const float* __restrict__ wsc,
                                               const float* __restrict__ W,
                                               float* __restrict__ out) {
    const int tid = threadIdx.x;
    const int nk  = blockIdx.x & 127;
    const int mp  = blockIdx.x >> 7;
    const int n   = nk >> 4, k = nk & 15;
    const int m0  = 2*mp;

    __shared__ float cl[2][16];
    __shared__ float red[4][2];
    if (tid < 2) {          // softmax over b of W[m, b, k]
        const int m = m0 + tid;
        float w[16], mx = -1e30f;
        #pragma unroll
        for (int b = 0; b < 16; ++b) {
            w[b] = W[m*256 + b*16 + k];
            mx = fmaxf(mx, w[b]);
        }
        float sum = 0.f;
        #pragma unroll
        for (int b = 0; b < 16; ++b) { w[b] = __expf(w[b] - mx); sum += w[b]; }
        const float inv = 1.f / sum;
        #pragma unroll
        for (int b = 0; b < 16; ++b) cl[tid][b] = w[b] * inv;
    }
    __syncthreads();

    float c0[16], c1[16];
    #pragma unroll
    for (int b = 0; b < 16; ++b) { c0[b] = cl[0][b]; c1[b] = cl[1][b]; }

    float U[16], sa[16], sb[16];
    #pragma unroll
    for (int j = 0; j < 16; ++j) { U[j] = 0.f; sa[j] = 0.f; sb[j] = 0.f; }

    const float* ub = wsc + WS_U + (nk << 12) + (tid << 4);
    for (int b = 0; b < 16; ++b) {
        const float* p = ub + ((size_t)b << 19);   // b stride = 128*4096
        float uv[16];
        #pragma unroll
        for (int q = 0; q < 4; ++q) {
            float4 v = *(const float4*)(p + 4*q);
            uv[4*q+0]=v.x; uv[4*q+1]=v.y; uv[4*q+2]=v.z; uv[4*q+3]=v.w;
        }
        const float ca = c0[b], cb = c1[b];
        #pragma unroll
        for (int j = 0; j < 16; ++j) {
            U[j]  += uv[j];
            sa[j] = fmaf(ca, uv[j], sa[j]);
            sb[j] = fmaf(cb, uv[j], sb[j]);
        }
    }

    // iteration 0
    float pa = 0.f, pb = 0.f;
    #pragma unroll
    for (int j = 0; j < 16; ++j) { pa = fmaf(sa[j], sa[j], pa); pb = fmaf(sb[j], sb[j], pb); }
    block_sum2(pa, pb, red, tid);
    const float r0a = __fsqrt_rn(pa) / (1.f + pa);
    const float r0b = __fsqrt_rn(pb) / (1.f + pb);

    // s1 = s0*(1 + r0*s0*U)
    float s1a[16], s1b[16];
    pa = 0.f; pb = 0.f;
    #pragma unroll
    for (int j = 0; j < 16; ++j) {
        s1a[j] = sa[j] * fmaf(r0a*sa[j], U[j], 1.f);
        s1b[j] = sb[j] * fmaf(r0b*sb[j], U[j], 1.f);
        pa = fmaf(s1a[j], s1a[j], pa); pb = fmaf(s1b[j], s1b[j], pb);
    }
    block_sum2(pa, pb, red, tid);
    const float r1a = __fsqrt_rn(pa) / (1.f + pa);
    const float r1b = __fsqrt_rn(pb) / (1.f + pb);

    // s2 = s0 + r1*s1^2*U
    pa = 0.f; pb = 0.f;
    #pragma unroll
    for (int j = 0; j < 16; ++j) {
        s1a[j] = fmaf(r1a*s1a[j]*s1a[j], U[j], sa[j]);   // reuse s1 as s2
        s1b[j] = fmaf(r1b*s1b[j]*s1b[j], U[j], sb[j]);
        pa = fmaf(s1a[j], s1a[j], pa); pb = fmaf(s1b[j], s1b[j], pb);
    }
    block_sum2(pa, pb, red, tid);
    const float r2a = __fsqrt_rn(pa) / (1.f + pa);
    const float r2b = __fsqrt_rn(pb) / (1.f + pb);

    // out[m,k,n,s] = s2 * r2
    float4* poa = (float4*)(out + (size_t)((((m0  )*16 + k)*8 + n) << 12) + (tid << 4));
    float4* pob = (float4*)(out + (size_t)((((m0+1)*16 + k)*8 + n) << 12) + (tid << 4));
    #pragma unroll
    for (int q = 0; q < 4; ++q) {
        poa[q] = make_float4(s1a[4*q+0]*r2a, s1a[4*q+1]*r2a, s1a[4*q+2]*r2a, s1a[4*q+3]*r2a);
        pob[q] = make_float4(s1b[4*q+0]*r2b, s1b[4*q+1]*r2b, s1b[4*q+2]*r2b, s1b[4*q+3]*r2b);
    }
}

extern "C" void kernel_launch(void* const* d_in, const int* in_sizes, int n_in,
                              void* d_out, int out_size, void* d_ws, size_t ws_size,
                              hipStream_t stream) {
    const float* x      = (const float*)d_in[0];
    const float* conv_w = (const float*)d_in[1];
    const float* conv_b = (const float*)d_in[2];
    const float* caps_w = (const float*)d_in[3];
    const float* caps_b = (const float*)d_in[4];
    const float* W      = (const float*)d_in[5];
    float* ws  = (float*)d_ws;
    float* out = (float*)d_out;

    hipLaunchKernelGGL(k_cw,    dim3(128),  dim3(256), 0, stream, caps_w, conv_w, conv_b, caps_b, ws);
    hipLaunchKernelGGL(k_conv,  dim3(2048), dim3(256), 0, stream, x, ws, ws);
    hipLaunchKernelGGL(k_route, dim3(512),  dim3(256), 0, stream, ws, W, out);
}